// Round 9
// baseline (1051.165 us; speedup 1.0000x reference)
//
#include <hip/hip_runtime.h>

#define NB_B 4
#define NB_L 8
#define NB_N 2048
#define NB_C 32
#define NB_M 1024

// workspace layout (float offsets)
#define ANCH_OFF  0          // 32*1024*3 = 98304
#define FT_OFF    98304      // 32*2048*32 = 2097152
#define XRAW_OFF  2195456    // 8*4*1024*192 = 6291456
#define STATS_OFF 8486912    // 2*1536 = 3072

// ---------------------------------------------------------------- FPS helpers
__device__ __forceinline__ double u2d(unsigned long long u) {
  return __longlong_as_double((long long)u);
}
__device__ __forceinline__ unsigned long long d2u(double d) {
  return (unsigned long long)__double_as_longlong(d);
}
// key = (f32bits(dist) << 32) | inv. dist in [0, FLT_MAX] ensures the f64
// view is positive finite (exponent field never all-ones, sign 0), so f64
// ordering == u64 ordering and f64 equality == bit equality (no +/-0 alias:
// key==0 would need dist==0 AND inv==0, impossible since inv>=0x7FFFF800).
__device__ __forceinline__ double pack_dk(float d, unsigned inv) {
  return u2d(((unsigned long long)__float_as_uint(d) << 32) | inv);
}

#define DPP_XOR1 0xB1   // quad_perm [1,0,3,2]
#define DPP_XOR2 0x4E   // quad_perm [2,3,0,1]
#define DPP_HMIR 0x141  // row_half_mirror (xor4 within 8)
#define DPP_MIR  0x140  // row_mirror (xor8 within 16)

template <int CTRL>
__device__ __forceinline__ double dpp_max_f64(double v) {
  int lo = __double2loint(v), hi = __double2hiint(v);
  int plo = __builtin_amdgcn_update_dpp(0, lo, CTRL, 0xF, 0xF, false);
  int phi = __builtin_amdgcn_update_dpp(0, hi, CTRL, 0xF, 0xF, false);
  return fmax(v, __hiloint2double(phi, plo));
}

// argmax step with position payload — pure VALU (DPP + cndmask)
template <int CTRL>
__device__ __forceinline__ void pstep(double& g, float& x, float& y, float& z) {
  int lo = __double2loint(g), hi = __double2hiint(g);
  int plo = __builtin_amdgcn_update_dpp(0, lo, CTRL, 0xF, 0xF, false);
  int phi = __builtin_amdgcn_update_dpp(0, hi, CTRL, 0xF, 0xF, false);
  int oxb = __builtin_amdgcn_update_dpp(0, __float_as_int(x), CTRL, 0xF, 0xF, false);
  int oyb = __builtin_amdgcn_update_dpp(0, __float_as_int(y), CTRL, 0xF, 0xF, false);
  int ozb = __builtin_amdgcn_update_dpp(0, __float_as_int(z), CTRL, 0xF, 0xF, false);
  double og = __hiloint2double(phi, plo);
  bool take = og > g;
  g = take ? og : g;
  x = take ? __int_as_float(oxb) : x;
  y = take ? __int_as_float(oyb) : y;
  z = take ? __int_as_float(ozb) : z;
}

#define FPS_T 512

// ---------------------------------------------------------------- fps + transpose
// blocks 0..31: FPS (one cloud each). blocks 32..1055: feature transpose
// (runs concurrently on the CUs FPS leaves idle).
__global__ __launch_bounds__(FPS_T) void fps_transpose_kernel(
    const float* __restrict__ xyzs, const float* __restrict__ features,
    float* __restrict__ ft, float* __restrict__ anchors,
    float* __restrict__ d_out) {
  __shared__ __align__(16) unsigned char smem[32 * 1024 + 512 + 1024];
  int t = threadIdx.x;
  if (blockIdx.x >= 32) {
    // ---------------- transpose: ft[b][fl][n][c] = features[b][fl][c][n]
    float(*tile)[65] = (float(*)[65])smem;
    int tb = blockIdx.x - 32;
    int frame = tb >> 5;
    int n0 = (tb & 31) * 64;
    const float* src = features + (size_t)frame * NB_C * NB_N;
    if (t < 256) {
#pragma unroll
      for (int i = 0; i < 8; ++i) {
        int q = t + i * 256;
        int c = q >> 6, n = q & 63;
        tile[c][n] = src[c * NB_N + n0 + n];
      }
    }
    __syncthreads();
    if (t < 256) {
      float* dst = ft + ((size_t)frame * NB_N + n0) * NB_C;
      int n = t >> 2, c0 = (t & 3) * 8;
      float v[8];
#pragma unroll
      for (int i = 0; i < 8; ++i) v[i] = tile[c0 + i][n];
      float4 w0 = {v[0], v[1], v[2], v[3]};
      float4 w1 = {v[4], v[5], v[6], v[7]};
      *(float4*)(dst + n * NB_C + c0) = w0;
      *(float4*)(dst + n * NB_C + c0 + 4) = w1;
    }
    return;
  }
  // ---------------- FPS
  float4* pos4 = (float4*)smem;                                   // 32 KB
  unsigned long long* keys = (unsigned long long*)(smem + 32768); // [2][32]
  float4* posl = (float4*)(smem + 32768 + 512);                   // [2][32]
  int cloud = blockIdx.x;               // b*L + l
  int w = t >> 6;
  int lane = t & 63;
  const float* xyz = xyzs + (size_t)cloud * NB_N * 3;
  for (int i = t; i < NB_N; i += FPS_T) {
    float x = xyz[i * 3 + 0];
    float y = xyz[i * 3 + 1];
    float z = xyz[i * 3 + 2];
    pos4[i] = make_float4(x, y, z, 0.f);
  }
  __syncthreads();
  float px[4], py[4], pz[4];
  double Kd[4];
  unsigned inv[4];
#pragma unroll
  for (int j = 0; j < 4; ++j) {
    int n = j * FPS_T + t;
    float4 p = pos4[n];
    px[j] = p.x; py[j] = p.y; pz[j] = p.z;
    inv[j] = 0x7FFFFFFFu - (unsigned)n;
    Kd[j] = pack_dk(3.402823466e38f, inv[j]);
  }
  int last = 0;
  int h0 = 0, h1 = 0;
  float4 sp = pos4[0];
  float lx = sp.x, ly = sp.y, lz = sp.z;
  int sidx = w * 4 + (lane >> 4);        // this lane's slot if it wins its group
  int t512 = t + 512;
  for (int m = 0; m < NB_M; ++m) {
    // reference emits the incoming seed at step m; capture in registers
    h0 = (m == t) ? last : h0;
    h1 = (m == t512) ? last : h1;
    int par = m & 1;
    double best = u2d(0ull);
#pragma unroll
    for (int j = 0; j < 4; ++j) {
      // exact reference arithmetic: no FMA contraction, (dx^2+dy^2)+dz^2
      float dx = __fsub_rn(px[j], lx);
      float dy = __fsub_rn(py[j], ly);
      float dz = __fsub_rn(pz[j], lz);
      float d = __fadd_rn(__fadd_rn(__fmul_rn(dx, dx), __fmul_rn(dy, dy)),
                          __fmul_rn(dz, dz));
      Kd[j] = fmin(Kd[j], pack_dk(d, inv[j]));   // v_min_f64: exact key min
      best = fmax(best, Kd[j]);                  // v_max_f64: exact key max
    }
    double lbest = best;                         // this lane's max (pre-DPP)
    // reduce to 16-lane-group maxima — pure DPP + f64 max
    best = dpp_max_f64<DPP_XOR1>(best);
    best = dpp_max_f64<DPP_XOR2>(best);
    best = dpp_max_f64<DPP_HMIR>(best);
    best = dpp_max_f64<DPP_MIR>(best);
    // unique winner lane of each 16-group writes key + position from registers
    float sx = px[0], sy = py[0], sz = pz[0];
    sx = (Kd[1] == lbest) ? px[1] : sx;
    sy = (Kd[1] == lbest) ? py[1] : sy;
    sz = (Kd[1] == lbest) ? pz[1] : sz;
    sx = (Kd[2] == lbest) ? px[2] : sx;
    sy = (Kd[2] == lbest) ? py[2] : sy;
    sz = (Kd[2] == lbest) ? pz[2] : sz;
    sx = (Kd[3] == lbest) ? px[3] : sx;
    sy = (Kd[3] == lbest) ? py[3] : sy;
    sz = (Kd[3] == lbest) ? pz[3] : sz;
    if (lbest == best) {
      keys[par * 32 + sidx] = d2u(best);
      posl[par * 32 + sidx] = make_float4(sx, sy, sz, 0.f);
    }
    __syncthreads();
    // lane reads a PAIR of slots (3 parallel b128 loads), merges, then 4
    // payload-DPP steps all-reduce key+position — no dependent pos4 read
    int pi = par * 32 + (lane & 15) * 2;
    ulonglong2 kp = *(const ulonglong2*)&keys[pi];
    float4 pa = posl[pi];
    float4 pb = posl[pi + 1];
    double ka = u2d(kp.x), kb = u2d(kp.y);
    bool tk = kb > ka;
    double g = tk ? kb : ka;
    float gx = tk ? pb.x : pa.x;
    float gy = tk ? pb.y : pa.y;
    float gz = tk ? pb.z : pa.z;
    pstep<DPP_XOR1>(g, gx, gy, gz);
    pstep<DPP_XOR2>(g, gx, gy, gz);
    pstep<DPP_HMIR>(g, gx, gy, gz);
    pstep<DPP_MIR>(g, gx, gy, gz);
    last = 0x7FFFFFFF - __double2loint(g);
    lx = gx; ly = gy; lz = gz;
  }
  {
    float4 p = pos4[h0];
    size_t o = ((size_t)cloud * NB_M + t) * 3;
    anchors[o + 0] = p.x; anchors[o + 1] = p.y; anchors[o + 2] = p.z;
    d_out[o + 0] = p.x;   d_out[o + 1] = p.y;   d_out[o + 2] = p.z;
    float4 q = pos4[h1];
    size_t o2 = ((size_t)cloud * NB_M + t512) * 3;
    anchors[o2 + 0] = q.x; anchors[o2 + 1] = q.y; anchors[o2 + 2] = q.z;
    d_out[o2 + 0] = q.x;   d_out[o2 + 1] = q.y;   d_out[o2 + 2] = q.z;
  }
}

// ---------------------------------------------------------------- ball query + conv
__device__ __forceinline__ float rdlane(float v, int l) {
  return __int_as_float(__builtin_amdgcn_readlane(__float_as_int(v), l));
}

#define BQ_WAVES 4
#define BQ_TPW 4    // tasks per wave; 4 | 1024 so a wave's tasks share (cloud, o)

__global__ __launch_bounds__(256) void bq_conv_kernel(
    const float* __restrict__ xyzs, const float* __restrict__ ft,
    const float* __restrict__ anchors, const float* __restrict__ conv_d_w,
    const float* __restrict__ conv_f_w, float* __restrict__ x_raw) {
  int w = threadIdx.x >> 6, lane = threadIdx.x & 63;
  int gw = blockIdx.x * BQ_WAVES + w;
  int task0 = gw * BQ_TPW;                // cloud*3072 + o*1024 + m
  int cloud = task0 / 3072;
  int rem = task0 - cloud * 3072;
  int o = rem >> 10, m0 = rem & 1023;
  int b = cloud >> 3, l = cloud & 7;
  int nl = l + o - 1;
  __shared__ int list_s[BQ_WAVES][32];
  __shared__ __align__(16) float disp_s[BQ_WAVES][32][4];
  float* xbase = x_raw + ((size_t)(l * NB_B + b) * NB_M + m0) * 192 + o * 64;
  if (nl < 0 || nl >= NB_L) {             // zero temporal padding frame: exact 0
#pragma unroll
    for (int t4 = 0; t4 < BQ_TPW; ++t4) xbase[(size_t)t4 * 192 + lane] = 0.0f;
    return;
  }
  // weights for this lane's output channel — loaded ONCE for all 4 tasks
  const float4* wf4 = (const float4*)(conv_f_w + lane * 32);
  float wf[32];
#pragma unroll
  for (int i = 0; i < 8; ++i) {
    float4 v = wf4[i];
    wf[i * 4 + 0] = v.x; wf[i * 4 + 1] = v.y;
    wf[i * 4 + 2] = v.z; wf[i * 4 + 3] = v.w;
  }
  float wd0 = conv_d_w[lane * 3 + 0];
  float wd1 = conv_d_w[lane * 3 + 1];
  float wd2 = conv_d_w[lane * 3 + 2];

  const float* nb = xyzs + (size_t)(b * NB_L + nl) * NB_N * 3;
  const float* ftf = ft + (size_t)(b * NB_L + nl) * NB_N * NB_C + (lane & 31);
  unsigned long long lmlt = (1ull << lane) - 1ull;
  int kbase = (lane >> 5) << 4;

  for (int t4 = 0; t4 < BQ_TPW; ++t4) {
    int m = m0 + t4;
    const float* ap = anchors + ((size_t)cloud * NB_M + m) * 3;
    float ax = ap[0], ay = ap[1], az = ap[2];

    // ---- ball query: first 32 indices (ascending) with d2 < 0.04
    // batches of 512 points; within a batch all 24 loads issue in parallel
    int count = 0;
    for (int batch = 0; batch < 4; ++batch) {
      unsigned long long bm[8];
#pragma unroll
      for (int c2 = 0; c2 < 8; ++c2) {
        int n = batch * 512 + c2 * 64 + lane;
        float x = nb[n * 3 + 0], y = nb[n * 3 + 1], z = nb[n * 3 + 2];
        float dx = __fsub_rn(ax, x);
        float dy = __fsub_rn(ay, y);
        float dz = __fsub_rn(az, z);
        float d2 = __fadd_rn(__fadd_rn(__fmul_rn(dx, dx), __fmul_rn(dy, dy)),
                             __fmul_rn(dz, dz));
        bm[c2] = __ballot(d2 < 0.04f);
      }
#pragma unroll
      for (int c2 = 0; c2 < 8; ++c2) {
        bool hit = (bm[c2] >> lane) & 1;
        int pos = count + __popcll(bm[c2] & lmlt);
        if (hit && pos < 32) list_s[w][pos] = batch * 512 + c2 * 64 + lane;
        count += __popcll(bm[c2]);
      }
      if (count >= 32) break;
    }
    asm volatile("s_waitcnt lgkmcnt(0)" ::: "memory");
    int cnt = count < 32 ? count : 32;
    int first = (cnt > 0) ? list_s[w][0] : 0;

    // ---- displacement for sample k = lane&31 (lanes 32..63 mirror)
    int k = lane & 31;
    int idxk = (k < cnt) ? list_s[w][k] : first;
    float bx = nb[idxk * 3 + 0], by = nb[idxk * 3 + 1], bz = nb[idxk * 3 + 2];
    float d0 = __fsub_rn(bx, ax);
    float d1 = __fsub_rn(by, ay);
    float d2v = __fsub_rn(bz, az);
    if (lane < 32) *(float4*)&disp_s[w][lane][0] = make_float4(d0, d1, d2v, 0.f);
    asm volatile("s_waitcnt lgkmcnt(0)" ::: "memory");

    // ---- G = sum_k f_k * disp_k^T  (32c x 3), split k across wave halves
    float G0 = 0.f, G1 = 0.f, G2 = 0.f;
#pragma unroll 8
    for (int i = 0; i < 16; ++i) {
      int kk = kbase + i;
      int ik = (kk < cnt) ? list_s[w][kk] : first;
      float fv = ftf[(size_t)ik * NB_C];
      float4 dd = *(const float4*)&disp_s[w][kk][0];
      G0 = fmaf(fv, dd.x, G0);
      G1 = fmaf(fv, dd.y, G1);
      G2 = fmaf(fv, dd.z, G2);
    }
    G0 += __shfl_xor(G0, 32);
    G1 += __shfl_xor(G1, 32);
    G2 += __shfl_xor(G2, 32);

    // ---- out[oc] = sum_c wf[oc,c] * (G[c,:] . wd[oc,:])
    float acc = 0.f;
#pragma unroll
    for (int cc = 0; cc < 32; ++cc) {
      float g0 = rdlane(G0, cc);
      float g1 = rdlane(G1, cc);
      float g2 = rdlane(G2, cc);
      float tt = fmaf(g2, wd2, fmaf(g1, wd1, g0 * wd0));
      acc = fmaf(wf[cc], tt, acc);
    }
    xbase[(size_t)t4 * 192 + lane] = acc;
  }
}

// ---------------------------------------------------------------- BN stats
__global__ __launch_bounds__(192) void bn_stats_kernel(const float* __restrict__ x_raw,
                                                       float* __restrict__ stats) {
  int bid = blockIdx.x;                  // 8 l * 4 b * 4 mt = 128
  int mt = bid & 3, bb = (bid >> 2) & 3, l = bid >> 4;
  int c = threadIdx.x;                   // 0..191
  const float* p = x_raw + ((size_t)(l * NB_B + bb) * NB_M + mt * 256) * 192 + c;
  float s = 0.f, s2 = 0.f;
  for (int i = 0; i < 256; ++i) {
    float v = p[(size_t)i * 192];
    s += v;
    s2 = fmaf(v, v, s2);
  }
  atomicAdd(&stats[l * 192 + c], s);
  atomicAdd(&stats[1536 + l * 192 + c], s2);
}

// ---------------------------------------------------------------- BN apply + temporal GEMM
__global__ __launch_bounds__(256) void final_kernel(
    const float* __restrict__ x_raw, const float* __restrict__ stats,
    const float* __restrict__ gamma, const float* __restrict__ beta,
    const float* __restrict__ tw, float* __restrict__ out) {
  __shared__ __align__(16) float xn[32 * 192];
  __shared__ __align__(16) float wt[64 * 132];
  __shared__ float sc[192], sh[192];
  int cloud = blockIdx.x >> 5;           // b*L + l
  int mt = blockIdx.x & 31;
  int b = cloud >> 3, l = cloud & 7;
  int m0 = mt * 32;
  int t = threadIdx.x;
  if (t < 192) {
    float mean = stats[l * 192 + t] * (1.0f / 4096.0f);
    float ex2 = stats[1536 + l * 192 + t] * (1.0f / 4096.0f);
    float var = fmaxf(ex2 - mean * mean, 0.0f);
    float g = gamma[t] / sqrtf(var + 1e-5f);
    sc[t] = g;
    sh[t] = fmaf(-mean, g, beta[t]);
  }
  __syncthreads();
  const float* xp = x_raw + ((size_t)(l * NB_B + b) * NB_M + m0) * 192;
#pragma unroll
  for (int i = 0; i < 24; ++i) {
    int q = t + i * 256;
    int cc = q % 192;
    float v = xp[q];
    xn[q] = fmaxf(fmaf(v, sc[cc], sh[cc]), 0.0f);
  }
  float acc[4][4];
#pragma unroll
  for (int i = 0; i < 4; ++i)
#pragma unroll
    for (int j = 0; j < 4; ++j) acc[i][j] = 0.f;
  int o0 = (t & 31) * 4;
  int mg = (t >> 5) * 4;
  for (int kt = 0; kt < 3; ++kt) {
    __syncthreads();
#pragma unroll
    for (int i = 0; i < 32; ++i) {
      int q = t + i * 256;
      int oo = q >> 6, kk = q & 63;
      wt[kk * 132 + oo] = tw[oo * 192 + kt * 64 + kk];
    }
    __syncthreads();
#pragma unroll
    for (int kk = 0; kk < 64; kk += 4) {
      float a[4][4], bb2[4][4];
#pragma unroll
      for (int mi = 0; mi < 4; ++mi) {
        float4 v = *(const float4*)&xn[(mg + mi) * 192 + kt * 64 + kk];
        a[mi][0] = v.x; a[mi][1] = v.y; a[mi][2] = v.z; a[mi][3] = v.w;
      }
#pragma unroll
      for (int j = 0; j < 4; ++j) {
        float4 v = *(const float4*)&wt[(kk + j) * 132 + o0];
        bb2[j][0] = v.x; bb2[j][1] = v.y; bb2[j][2] = v.z; bb2[j][3] = v.w;
      }
#pragma unroll
      for (int mi = 0; mi < 4; ++mi)
#pragma unroll
        for (int j = 0; j < 4; ++j)
#pragma unroll
          for (int oi = 0; oi < 4; ++oi)
            acc[mi][oi] = fmaf(a[mi][j], bb2[j][oi], acc[mi][oi]);
    }
  }
  float* op = out + 98304 + ((size_t)cloud * 128 + o0) * NB_M + m0 + mg;
#pragma unroll
  for (int oi = 0; oi < 4; ++oi) {
    float4 v = {acc[0][oi], acc[1][oi], acc[2][oi], acc[3][oi]};
    *(float4*)(op + (size_t)oi * NB_M) = v;
  }
}

// ---------------------------------------------------------------- launch
extern "C" void kernel_launch(void* const* d_in, const int* in_sizes, int n_in,
                              void* d_out, int out_size, void* d_ws, size_t ws_size,
                              hipStream_t stream) {
  const float* xyzs = (const float*)d_in[0];
  const float* features = (const float*)d_in[1];
  const float* conv_d_w = (const float*)d_in[2];
  const float* conv_f_w = (const float*)d_in[3];
  const float* bn_gamma = (const float*)d_in[4];
  const float* bn_beta = (const float*)d_in[5];
  const float* temporal_w = (const float*)d_in[6];
  float* ws = (float*)d_ws;
  float* anchors = ws + ANCH_OFF;
  float* ft = ws + FT_OFF;
  float* xraw = ws + XRAW_OFF;
  float* stats = ws + STATS_OFF;
  float* out = (float*)d_out;

  hipMemsetAsync(stats, 0, 3072 * sizeof(float), stream);
  // blocks 0..31 = FPS; blocks 32..1055 = transpose (overlapped on idle CUs)
  fps_transpose_kernel<<<1056, FPS_T, 0, stream>>>(xyzs, features, ft,
                                                   anchors, out);
  // 98304 tasks / (4 waves * 4 tasks) = 6144 blocks
  bq_conv_kernel<<<6144, 256, 0, stream>>>(xyzs, ft, anchors, conv_d_w,
                                           conv_f_w, xraw);
  bn_stats_kernel<<<128, 192, 0, stream>>>(xraw, stats);
  final_kernel<<<1024, 256, 0, stream>>>(xraw, stats, bn_gamma, bn_beta,
                                         temporal_w, out);
}

// Round 10
// 741.081 us; speedup vs baseline: 1.4184x; 1.4184x over previous
//
#include <hip/hip_runtime.h>

#define NB_B 4
#define NB_L 8
#define NB_N 2048
#define NB_C 32
#define NB_M 1024

// workspace layout (float offsets)
#define ANCH_OFF  0          // 32*1024*3 = 98304
#define FT_OFF    98304      // 32*2048*32 = 2097152
#define XRAW_OFF  2195456    // 8*4*1024*192 = 6291456
#define STATS_OFF 8486912    // 2*1536 = 3072

// ---------------------------------------------------------------- FPS helpers
__device__ __forceinline__ double u2d(unsigned long long u) {
  return __longlong_as_double((long long)u);
}
__device__ __forceinline__ unsigned long long d2u(double d) {
  return (unsigned long long)__double_as_longlong(d);
}
// key = (f32bits(dist) << 32) | inv. dist in [0, FLT_MAX] ensures the f64
// view is positive finite (exponent never all-ones, sign 0), so f64 ordering
// == u64 ordering of the packed key: v_min/max_f64 do exact 64-bit key select.
__device__ __forceinline__ double pack_dk(float d, unsigned inv) {
  return u2d(((unsigned long long)__float_as_uint(d) << 32) | inv);
}

#define DPP_XOR1 0xB1   // quad_perm [1,0,3,2]
#define DPP_XOR2 0x4E   // quad_perm [2,3,0,1]
#define DPP_HMIR 0x141  // row_half_mirror (xor4 within 8)
#define DPP_MIR  0x140  // row_mirror (xor8 within 16)

template <int CTRL>
__device__ __forceinline__ double dpp_max_f64(double v) {
  int lo = __double2loint(v), hi = __double2hiint(v);
  int plo = __builtin_amdgcn_update_dpp(0, lo, CTRL, 0xF, 0xF, false);
  int phi = __builtin_amdgcn_update_dpp(0, hi, CTRL, 0xF, 0xF, false);
  return fmax(v, __hiloint2double(phi, plo));
}

#define FPS_T 512

// ---------------------------------------------------------------- fps + transpose
// blocks 0..31: FPS (one cloud each). blocks 32..1055: feature transpose
// (runs concurrently on the CUs FPS leaves idle).
// FPS body is the round-7-measured 442us structure (single key-slot array,
// dependent pos4[last] read) — payload-slot variants regressed (bank conflicts).
__global__ __launch_bounds__(FPS_T) void fps_transpose_kernel(
    const float* __restrict__ xyzs, const float* __restrict__ features,
    float* __restrict__ ft, float* __restrict__ anchors,
    float* __restrict__ d_out) {
  __shared__ __align__(16) unsigned char smem[32 * 1024 + 512];
  int t = threadIdx.x;
  if (blockIdx.x >= 32) {
    // ---------------- transpose: ft[b][fl][n][c] = features[b][fl][c][n]
    float(*tile)[65] = (float(*)[65])smem;
    int tb = blockIdx.x - 32;
    int frame = tb >> 5;
    int n0 = (tb & 31) * 64;
    const float* src = features + (size_t)frame * NB_C * NB_N;
    if (t < 256) {
#pragma unroll
      for (int i = 0; i < 8; ++i) {
        int q = t + i * 256;
        int c = q >> 6, n = q & 63;
        tile[c][n] = src[c * NB_N + n0 + n];
      }
    }
    __syncthreads();
    if (t < 256) {
      float* dst = ft + ((size_t)frame * NB_N + n0) * NB_C;
      int n = t >> 2, c0 = (t & 3) * 8;
      float v[8];
#pragma unroll
      for (int i = 0; i < 8; ++i) v[i] = tile[c0 + i][n];
      float4 w0 = {v[0], v[1], v[2], v[3]};
      float4 w1 = {v[4], v[5], v[6], v[7]};
      *(float4*)(dst + n * NB_C + c0) = w0;
      *(float4*)(dst + n * NB_C + c0 + 4) = w1;
    }
    return;
  }
  // ---------------- FPS
  float4* pos4 = (float4*)smem;                                   // 32 KB
  unsigned long long* slots = (unsigned long long*)(smem + 32768);  // [2][32]
  int cloud = blockIdx.x;               // b*L + l
  int w = t >> 6;
  int lane = t & 63;
  const float* xyz = xyzs + (size_t)cloud * NB_N * 3;
  for (int i = t; i < NB_N; i += FPS_T) {
    float x = xyz[i * 3 + 0];
    float y = xyz[i * 3 + 1];
    float z = xyz[i * 3 + 2];
    pos4[i] = make_float4(x, y, z, 0.f);
  }
  __syncthreads();
  float px[4], py[4], pz[4];
  double Kd[4];
  unsigned inv[4];
#pragma unroll
  for (int j = 0; j < 4; ++j) {
    int n = j * FPS_T + t;
    float4 p = pos4[n];
    px[j] = p.x; py[j] = p.y; pz[j] = p.z;
    inv[j] = 0x7FFFFFFFu - (unsigned)n;
    Kd[j] = pack_dk(3.402823466e38f, inv[j]);
  }
  int last = 0;
  int h0 = 0, h1 = 0;
  float4 sp = pos4[0];
  float lx = sp.x, ly = sp.y, lz = sp.z;
  int sidx = w * 4 + (lane >> 4);        // this lane's slot if lane&15==0
  bool swrite = (lane & 15) == 0;
  int t512 = t + 512;
  for (int m = 0; m < NB_M; ++m) {
    // reference emits the incoming seed at step m; capture in registers
    h0 = (m == t) ? last : h0;
    h1 = (m == t512) ? last : h1;
    int par = m & 1;
    double best = u2d(0ull);
#pragma unroll
    for (int j = 0; j < 4; ++j) {
      // exact reference arithmetic: no FMA contraction, (dx^2+dy^2)+dz^2
      float dx = __fsub_rn(px[j], lx);
      float dy = __fsub_rn(py[j], ly);
      float dz = __fsub_rn(pz[j], lz);
      float d = __fadd_rn(__fadd_rn(__fmul_rn(dx, dx), __fmul_rn(dy, dy)),
                          __fmul_rn(dz, dz));
      Kd[j] = fmin(Kd[j], pack_dk(d, inv[j]));   // v_min_f64: exact key min
      best = fmax(best, Kd[j]);                  // v_max_f64: exact key max
    }
    // reduce to 16-lane-group maxima — pure DPP + f64 max
    best = dpp_max_f64<DPP_XOR1>(best);
    best = dpp_max_f64<DPP_XOR2>(best);
    best = dpp_max_f64<DPP_HMIR>(best);
    best = dpp_max_f64<DPP_MIR>(best);
    // 4 group-representatives per wave write 32 slots total
    if (swrite) slots[par * 32 + sidx] = d2u(best);
    __syncthreads();
    // every lane reads a PAIR of slots (one b128), then 4 DPP steps finish
    ulonglong2 pr2 = *(const ulonglong2*)&slots[par * 32 + (lane & 15) * 2];
    double g = fmax(u2d(pr2.x), u2d(pr2.y));
    g = dpp_max_f64<DPP_XOR1>(g);
    g = dpp_max_f64<DPP_XOR2>(g);
    g = dpp_max_f64<DPP_HMIR>(g);
    g = dpp_max_f64<DPP_MIR>(g);
    last = 0x7FFFFFFF - __double2loint(g);
    float4 p = pos4[last];
    lx = p.x; ly = p.y; lz = p.z;
  }
  {
    float4 p = pos4[h0];
    size_t o = ((size_t)cloud * NB_M + t) * 3;
    anchors[o + 0] = p.x; anchors[o + 1] = p.y; anchors[o + 2] = p.z;
    d_out[o + 0] = p.x;   d_out[o + 1] = p.y;   d_out[o + 2] = p.z;
    float4 q = pos4[h1];
    size_t o2 = ((size_t)cloud * NB_M + t512) * 3;
    anchors[o2 + 0] = q.x; anchors[o2 + 1] = q.y; anchors[o2 + 2] = q.z;
    d_out[o2 + 0] = q.x;   d_out[o2 + 1] = q.y;   d_out[o2 + 2] = q.z;
  }
}

// ---------------------------------------------------------------- ball query + conv
__device__ __forceinline__ float rdlane(float v, int l) {
  return __int_as_float(__builtin_amdgcn_readlane(__float_as_int(v), l));
}

#define BQ_WAVES 4
#define BQ_TPW 4    // tasks per wave; block = 16 consecutive tasks, 16 | 1024
                    // so ALL waves in a block share (cloud, o) -> same frame

__global__ __launch_bounds__(256) void bq_conv_kernel(
    const float* __restrict__ xyzs, const float* __restrict__ ft,
    const float* __restrict__ anchors, const float* __restrict__ conv_d_w,
    const float* __restrict__ conv_f_w, float* __restrict__ x_raw) {
  int w = threadIdx.x >> 6, lane = threadIdx.x & 63;
  int tid = threadIdx.x;
  int gw = blockIdx.x * BQ_WAVES + w;
  int task0 = gw * BQ_TPW;                // cloud*3072 + o*1024 + m
  int cloud = task0 / 3072;
  int rem = task0 - cloud * 3072;
  int o = rem >> 10, m0 = rem & 1023;
  int b = cloud >> 3, l = cloud & 7;
  int nl = l + o - 1;                     // uniform across the block
  __shared__ int list_s[BQ_WAVES][32];
  __shared__ __align__(16) float4 pos_l[NB_N];   // 32 KB: frame xyz, shared
  float* xbase = x_raw + ((size_t)(l * NB_B + b) * NB_M + m0) * 192 + o * 64;
  if (nl < 0 || nl >= NB_L) {             // zero temporal padding frame: exact 0
#pragma unroll
    for (int t4 = 0; t4 < BQ_TPW; ++t4) xbase[(size_t)t4 * 192 + lane] = 0.0f;
    return;                               // block-uniform: no barrier divergence
  }
  const float* nb = xyzs + (size_t)(b * NB_L + nl) * NB_N * 3;
  // ---- stage the frame's 2048 points into LDS once per block
  for (int i = tid; i < NB_N; i += 256) {
    float x = nb[i * 3 + 0], y = nb[i * 3 + 1], z = nb[i * 3 + 2];
    pos_l[i] = make_float4(x, y, z, 0.f);
  }
  __syncthreads();

  // weights for this lane's output channel — loaded ONCE for all 4 tasks
  const float4* wf4 = (const float4*)(conv_f_w + lane * 32);
  float wf[32];
#pragma unroll
  for (int i = 0; i < 8; ++i) {
    float4 v = wf4[i];
    wf[i * 4 + 0] = v.x; wf[i * 4 + 1] = v.y;
    wf[i * 4 + 2] = v.z; wf[i * 4 + 3] = v.w;
  }
  float wd0 = conv_d_w[lane * 3 + 0];
  float wd1 = conv_d_w[lane * 3 + 1];
  float wd2 = conv_d_w[lane * 3 + 2];

  const float* ftf = ft + (size_t)(b * NB_L + nl) * NB_N * NB_C + (lane & 31);
  unsigned long long lmlt = (1ull << lane) - 1ull;
  int kbase = (lane >> 5) << 4;

  for (int t4 = 0; t4 < BQ_TPW; ++t4) {
    int m = m0 + t4;
    const float* ap = anchors + ((size_t)cloud * NB_M + m) * 3;
    float ax = ap[0], ay = ap[1], az = ap[2];

    // ---- ball query: first 32 indices (ascending) with d2 < 0.04
    // batches of 512 points from LDS; all 8 ds_read_b128 issue in parallel
    int count = 0;
    for (int batch = 0; batch < 4; ++batch) {
      unsigned long long bm[8];
#pragma unroll
      for (int c2 = 0; c2 < 8; ++c2) {
        int n = batch * 512 + c2 * 64 + lane;
        float4 p = pos_l[n];
        float dx = __fsub_rn(ax, p.x);
        float dy = __fsub_rn(ay, p.y);
        float dz = __fsub_rn(az, p.z);
        float d2 = __fadd_rn(__fadd_rn(__fmul_rn(dx, dx), __fmul_rn(dy, dy)),
                             __fmul_rn(dz, dz));
        bm[c2] = __ballot(d2 < 0.04f);
      }
#pragma unroll
      for (int c2 = 0; c2 < 8; ++c2) {
        bool hit = (bm[c2] >> lane) & 1;
        int pos = count + __popcll(bm[c2] & lmlt);
        if (hit && pos < 32) list_s[w][pos] = batch * 512 + c2 * 64 + lane;
        count += __popcll(bm[c2]);
      }
      if (count >= 32) break;
    }
    asm volatile("s_waitcnt lgkmcnt(0)" ::: "memory");
    int cnt = count < 32 ? count : 32;
    int first = (cnt > 0) ? list_s[w][0] : 0;

    // ---- displacement for sample k = lane&31 (lanes 32..63 mirror)
    int k = lane & 31;
    int idxk = (k < cnt) ? list_s[w][k] : first;
    float4 pb = pos_l[idxk];
    float d0 = __fsub_rn(pb.x, ax);
    float d1 = __fsub_rn(pb.y, ay);
    float d2v = __fsub_rn(pb.z, az);

    // ---- G = sum_k f_k * disp_k^T  (32c x 3), split k across wave halves
    float G0 = 0.f, G1 = 0.f, G2 = 0.f;
#pragma unroll 8
    for (int i = 0; i < 16; ++i) {
      int kk = kbase + i;
      int ik = (kk < cnt) ? list_s[w][kk] : first;
      float fv = ftf[(size_t)ik * NB_C];
      float e0 = __shfl(d0, kk);
      float e1 = __shfl(d1, kk);
      float e2 = __shfl(d2v, kk);
      G0 = fmaf(fv, e0, G0);
      G1 = fmaf(fv, e1, G1);
      G2 = fmaf(fv, e2, G2);
    }
    G0 += __shfl_xor(G0, 32);
    G1 += __shfl_xor(G1, 32);
    G2 += __shfl_xor(G2, 32);

    // ---- out[oc] = sum_c wf[oc,c] * (G[c,:] . wd[oc,:])
    float acc = 0.f;
#pragma unroll
    for (int cc = 0; cc < 32; ++cc) {
      float g0 = rdlane(G0, cc);
      float g1 = rdlane(G1, cc);
      float g2 = rdlane(G2, cc);
      float tt = fmaf(g2, wd2, fmaf(g1, wd1, g0 * wd0));
      acc = fmaf(wf[cc], tt, acc);
    }
    xbase[(size_t)t4 * 192 + lane] = acc;
  }
}

// ---------------------------------------------------------------- BN stats
__global__ __launch_bounds__(192) void bn_stats_kernel(const float* __restrict__ x_raw,
                                                       float* __restrict__ stats) {
  int bid = blockIdx.x;                  // 8 l * 4 b * 4 mt = 128
  int mt = bid & 3, bb = (bid >> 2) & 3, l = bid >> 4;
  int c = threadIdx.x;                   // 0..191
  const float* p = x_raw + ((size_t)(l * NB_B + bb) * NB_M + mt * 256) * 192 + c;
  float s = 0.f, s2 = 0.f;
  for (int i = 0; i < 256; ++i) {
    float v = p[(size_t)i * 192];
    s += v;
    s2 = fmaf(v, v, s2);
  }
  atomicAdd(&stats[l * 192 + c], s);
  atomicAdd(&stats[1536 + l * 192 + c], s2);
}

// ---------------------------------------------------------------- BN apply + temporal GEMM
__global__ __launch_bounds__(256) void final_kernel(
    const float* __restrict__ x_raw, const float* __restrict__ stats,
    const float* __restrict__ gamma, const float* __restrict__ beta,
    const float* __restrict__ tw, float* __restrict__ out) {
  __shared__ __align__(16) float xn[32 * 192];
  __shared__ __align__(16) float wt[64 * 132];
  __shared__ float sc[192], sh[192];
  int cloud = blockIdx.x >> 5;           // b*L + l
  int mt = blockIdx.x & 31;
  int b = cloud >> 3, l = cloud & 7;
  int m0 = mt * 32;
  int t = threadIdx.x;
  if (t < 192) {
    float mean = stats[l * 192 + t] * (1.0f / 4096.0f);
    float ex2 = stats[1536 + l * 192 + t] * (1.0f / 4096.0f);
    float var = fmaxf(ex2 - mean * mean, 0.0f);
    float g = gamma[t] / sqrtf(var + 1e-5f);
    sc[t] = g;
    sh[t] = fmaf(-mean, g, beta[t]);
  }
  __syncthreads();
  const float* xp = x_raw + ((size_t)(l * NB_B + b) * NB_M + m0) * 192;
#pragma unroll
  for (int i = 0; i < 24; ++i) {
    int q = t + i * 256;
    int cc = q % 192;
    float v = xp[q];
    xn[q] = fmaxf(fmaf(v, sc[cc], sh[cc]), 0.0f);
  }
  float acc[4][4];
#pragma unroll
  for (int i = 0; i < 4; ++i)
#pragma unroll
    for (int j = 0; j < 4; ++j) acc[i][j] = 0.f;
  int o0 = (t & 31) * 4;
  int mg = (t >> 5) * 4;
  for (int kt = 0; kt < 3; ++kt) {
    __syncthreads();
#pragma unroll
    for (int i = 0; i < 32; ++i) {
      int q = t + i * 256;
      int oo = q >> 6, kk = q & 63;
      wt[kk * 132 + oo] = tw[oo * 192 + kt * 64 + kk];
    }
    __syncthreads();
#pragma unroll
    for (int kk = 0; kk < 64; kk += 4) {
      float a[4][4], bb2[4][4];
#pragma unroll
      for (int mi = 0; mi < 4; ++mi) {
        float4 v = *(const float4*)&xn[(mg + mi) * 192 + kt * 64 + kk];
        a[mi][0] = v.x; a[mi][1] = v.y; a[mi][2] = v.z; a[mi][3] = v.w;
      }
#pragma unroll
      for (int j = 0; j < 4; ++j) {
        float4 v = *(const float4*)&wt[(kk + j) * 132 + o0];
        bb2[j][0] = v.x; bb2[j][1] = v.y; bb2[j][2] = v.z; bb2[j][3] = v.w;
      }
#pragma unroll
      for (int mi = 0; mi < 4; ++mi)
#pragma unroll
        for (int j = 0; j < 4; ++j)
#pragma unroll
          for (int oi = 0; oi < 4; ++oi)
            acc[mi][oi] = fmaf(a[mi][j], bb2[j][oi], acc[mi][oi]);
    }
  }
  float* op = out + 98304 + ((size_t)cloud * 128 + o0) * NB_M + m0 + mg;
#pragma unroll
  for (int oi = 0; oi < 4; ++oi) {
    float4 v = {acc[0][oi], acc[1][oi], acc[2][oi], acc[3][oi]};
    *(float4*)(op + (size_t)oi * NB_M) = v;
  }
}

// ---------------------------------------------------------------- launch
extern "C" void kernel_launch(void* const* d_in, const int* in_sizes, int n_in,
                              void* d_out, int out_size, void* d_ws, size_t ws_size,
                              hipStream_t stream) {
  const float* xyzs = (const float*)d_in[0];
  const float* features = (const float*)d_in[1];
  const float* conv_d_w = (const float*)d_in[2];
  const float* conv_f_w = (const float*)d_in[3];
  const float* bn_gamma = (const float*)d_in[4];
  const float* bn_beta = (const float*)d_in[5];
  const float* temporal_w = (const float*)d_in[6];
  float* ws = (float*)d_ws;
  float* anchors = ws + ANCH_OFF;
  float* ft = ws + FT_OFF;
  float* xraw = ws + XRAW_OFF;
  float* stats = ws + STATS_OFF;
  float* out = (float*)d_out;

  hipMemsetAsync(stats, 0, 3072 * sizeof(float), stream);
  // blocks 0..31 = FPS; blocks 32..1055 = transpose (overlapped on idle CUs)
  fps_transpose_kernel<<<1056, FPS_T, 0, stream>>>(xyzs, features, ft,
                                                   anchors, out);
  // 98304 tasks / (4 waves * 4 tasks) = 6144 blocks
  bq_conv_kernel<<<6144, 256, 0, stream>>>(xyzs, ft, anchors, conv_d_w,
                                           conv_f_w, xraw);
  bn_stats_kernel<<<128, 192, 0, stream>>>(xraw, stats);
  final_kernel<<<1024, 256, 0, stream>>>(xraw, stats, bn_gamma, bn_beta,
                                         temporal_w, out);
}